// Round 5
// baseline (55.325 us; speedup 1.0000x reference)
//
#include <hip/hip_runtime.h>
#include <hip/hip_bf16.h>
#include <math.h>

#define HIDDEN 2048
#define NEXP   64
#define NTOK   16384

typedef __attribute__((ext_vector_type(8))) _Float16 f16x8;  // 8 f16 = 4 VGPR (MFMA A/B frag)
typedef __attribute__((ext_vector_type(4))) float   f32x4;   // MFMA C/D frag

// 2-way fp16 RNE split: x = h + l + O(2^-22). Residual exact (Sterbenz), l may be subnormal (ok).
__device__ __forceinline__ void split2_f16(float4 f0, float4 f1, f16x8& h, f16x8& l) {
    float e[8] = {f0.x, f0.y, f0.z, f0.w, f1.x, f1.y, f1.z, f1.w};
    f16x8 hv, lv;
#pragma unroll
    for (int i = 0; i < 8; ++i) {
        _Float16 hh = (_Float16)e[i];        // v_cvt_f16_f32 (RNE)
        float r = e[i] - (float)hh;          // exact residual
        hv[i] = hh;
        lv[i] = (_Float16)r;
    }
    h = hv; l = lv;
}

// ---------------- Kernel 0: w [64][2048] fp32 -> wh/wl f16x8 slots, pre-swizzled ----------------
// Slot (c, e, kgp) holds w[e][c*64 + (kgp^(e&7))*8 .. +7]; flat = c*512 + e*8 + kgp.
// Linear LDS image for global_load_lds; XOR keeps B ds_read_b128 at 2-way (free).
__global__ __launch_bounds__(256) void prep_kernel(
    const float* __restrict__ gw, uint4* __restrict__ wh, uint4* __restrict__ wl)
{
    const int gid = blockIdx.x * 256 + threadIdx.x;   // 0..16383
    const int c   = gid >> 9;
    const int e   = (gid >> 3) & 63;
    const int kgp = gid & 7;
    const int kg  = kgp ^ (e & 7);
    const float* src = gw + (size_t)e * HIDDEN + c * 64 + kg * 8;
    float4 s0 = *(const float4*)src;
    float4 s1 = *(const float4*)(src + 4);
    f16x8 h, l;
    split2_f16(s0, s1, h, l);
    wh[gid] = __builtin_bit_cast(uint4, h);
    wl[gid] = __builtin_bit_cast(uint4, l);
}

// ---------------- Fused kernel: MFMA GEMM (full K) + bias + top-2 + weights + mask ----------------
// R4 counters showed latency-bound (930 GB/s HBM, MfmaUtil 6.4%, all pipes idle): the per-chunk
// __syncthreads() drained vmcnt(0) = full vmem latency paid serially 32x/block.
// Fix (T4): ring-3 LDS buffers + counted s_waitcnt vmcnt(N) + raw s_barrier. Steady state keeps
// A(c+1) [4 ops] + STAGE(c+2) [4 ops] in flight across the barrier; vmcnt(8) retires only
// STAGE(c+1). Stage slack ~1.5 iterations instead of ~0.3; never drain to 0 in the loop.
// Grid 512 blocks x 256 threads (4 waves), 32 tokens/block, 2 blocks/CU, 2 waves/SIMD.
// Wave (tg=wv&1, eh=wv>>1): tokens tg*16..+16 x experts eh*32..+32 (2 egs, 6 MFMAs/ks).
#define STAGE(cg, bo)                                                                     \
    _Pragma("unroll")                                                                     \
    for (int rr = 0; rr < 2; ++rr) {                                                      \
        const int s = rr * 256 + tid;                                                     \
        __builtin_amdgcn_global_load_lds(                                                 \
            (const __attribute__((address_space(1))) void*)(wh + (size_t)(cg) * 512 + s), \
            (__attribute__((address_space(3))) void*)&Bs[(bo) + s], 16, 0, 0);            \
        __builtin_amdgcn_global_load_lds(                                                 \
            (const __attribute__((address_space(1))) void*)(wl + (size_t)(cg) * 512 + s), \
            (__attribute__((address_space(3))) void*)&Bs[(bo) + 512 + s], 16, 0, 0);      \
    }

__global__ __launch_bounds__(256, 2) void fused_kernel(
    const float* __restrict__ x,     // [NTOK, HIDDEN]
    const uint4* __restrict__ wh,    // [32][64][8] slots (f16 high plane)
    const uint4* __restrict__ wl,    // f16 low plane
    const float* __restrict__ bias_g,
    float* __restrict__ logits,
    float* __restrict__ weights,
    float* __restrict__ idxf,
    float* __restrict__ mask)
{
    __shared__ uint4 Bs[3 * 1024];   // ring-3 x (h|l x 512 slots) = 48 KB
    __shared__ float Ls[32][65];     // block's 32x64 logit tile (+1 pad)
    __shared__ int selA[32], selB[32];

    const int tid = threadIdx.x;
    const int l   = tid & 63;
    const int wv  = tid >> 6;                // 0..3
    const int tg  = wv & 1;                  // token group
    const int eh  = wv >> 1;                 // expert half (0: e<32, 1: e>=32)
    const int tb0 = blockIdx.x * 32;         // block token base
    const int t0  = tb0 + tg * 16;           // wave token base

    // A: lane l -> row t0+(l&15); k-group (l>>4)*8 within each 32-k step
    const float4* xp = (const float4*)(x + (size_t)(t0 + (l & 15)) * HIDDEN) + ((l >> 4) * 2);

    // B slot base: e=(l&15)+16*EG, kgp=((ks<<2)|(l>>4))^(l&7); ks XOR'd at use
    const int lb = ((l & 15) << 3) | ((l >> 4) ^ (l & 7));

    f32x4 acc1[2], acc2[2];          // [eg], actual expert group = eh*2+eg
#pragma unroll
    for (int eg = 0; eg < 2; ++eg) {
        acc1[eg] = (f32x4){0.f, 0.f, 0.f, 0.f};
        acc2[eg] = (f32x4){0.f, 0.f, 0.f, 0.f};
    }

    // prologue: stage chunk0 -> buf0 [4 ops], A(0) [4 ops], stage chunk1 -> buf1 [4 ops]
    STAGE(0, 0)
    float4 a0 = xp[0], a1 = xp[1], a2 = xp[8], a3 = xp[9];
    STAGE(1, 1024)
    asm volatile("s_waitcnt vmcnt(8)" ::: "memory");   // stage0 landed (A0+stage1 in flight)
    __builtin_amdgcn_s_barrier();
    __builtin_amdgcn_sched_barrier(0);

    const int nch = HIDDEN / 64;     // 32 chunks
    int rd = 0;                      // ring buffer holding chunk c
#pragma unroll 1
    for (int c = 0; c < nch; ++c) {
        const bool hasA = (c + 1 < nch);
        const bool hasS = (c + 2 < nch);

        // A(c+1) first (so the compiler's A(c)-wait leaves both stages in flight)
        float4 n0 = a0, n1 = a1, n2 = a2, n3 = a3;
        if (hasA) {
            const int fb = (c + 1) * 16;
            n0 = xp[fb + 0]; n1 = xp[fb + 1]; n2 = xp[fb + 8]; n3 = xp[fb + 9];
        }
        // STAGE(c+2) into buf (rd+2)%3 (that buffer's readers all retired before last barrier)
        if (hasS) {
            const int st = (rd + 2 >= 3) ? (rd - 1) : (rd + 2);
            STAGE(c + 2, st * 1024)
        }

        // compute chunk c from buf rd (compiler waits vmcnt for A(c) only)
#pragma unroll
        for (int ks = 0; ks < 2; ++ks) {
            f16x8 ah, al;
            split2_f16(ks ? a2 : a0, ks ? a3 : a1, ah, al);
            const int ib = rd * 1024 + (lb ^ (ks << 2));
#pragma unroll
            for (int eg = 0; eg < 2; ++eg) {
                const int ego = (eh * 2 + eg) * 128;
                f16x8 bh = __builtin_bit_cast(f16x8, Bs[ib + ego]);
                f16x8 bl = __builtin_bit_cast(f16x8, Bs[ib + 512 + ego]);
                acc1[eg] = __builtin_amdgcn_mfma_f32_16x16x32_f16(ah, bh, acc1[eg], 0, 0, 0); // hh
                acc2[eg] = __builtin_amdgcn_mfma_f32_16x16x32_f16(ah, bl, acc2[eg], 0, 0, 0); // hl
                acc2[eg] = __builtin_amdgcn_mfma_f32_16x16x32_f16(al, bh, acc2[eg], 0, 0, 0); // lh
            }
        }

        // retire STAGE(c+1) only; keep A(c+1)+STAGE(c+2) in flight across the barrier
        if (hasS) {
            asm volatile("s_waitcnt vmcnt(8)" ::: "memory");
        } else if (hasA) {
            asm volatile("s_waitcnt vmcnt(4)" ::: "memory");   // no STAGE(c+2) behind it
        }
        if (hasA) {
            __builtin_amdgcn_s_barrier();
            __builtin_amdgcn_sched_barrier(0);
        }

        a0 = n0; a1 = n1; a2 = n2; a3 = n3;
        rd = (rd + 1 >= 3) ? 0 : (rd + 1);
    }

    // ---- epilogue: logits tile to LDS (bias added)
    // reg (eg,i) -> row tg*16+(l>>4)*4+i, expert (eh*2+eg)*16+(l&15)
#pragma unroll
    for (int eg = 0; eg < 2; ++eg) {
        const int col = (eh * 2 + eg) * 16 + (l & 15);
        const float b = bias_g[col];
#pragma unroll
        for (int i = 0; i < 4; ++i)
            Ls[tg * 16 + (l >> 4) * 4 + i][col] = acc1[eg][i] + acc2[eg][i] + b;
    }
    __syncthreads();

    // logits to global, coalesced float4: 512 float4 across 256 threads
#pragma unroll
    for (int i = 0; i < 2; ++i) {
        const int idx = i * 256 + tid;
        const int row = idx >> 4;
        const int c4  = (idx & 15) << 2;
        float4 v;
        v.x = Ls[row][c4 + 0];
        v.y = Ls[row][c4 + 1];
        v.z = Ls[row][c4 + 2];
        v.w = Ls[row][c4 + 3];
        *(float4*)&logits[(size_t)(tb0 + row) * NEXP + c4] = v;
    }

    // top-2 per token (threads 0..31; bank = (t + e) mod 32 -> conflict-free)
    if (tid < 32) {
        const int t = tid;
        float best = -1e30f, second = -1e30f;
        int bi = 0, si = 0;
#pragma unroll
        for (int e = 0; e < NEXP; ++e) {
            float v = Ls[t][e];
            if (v > best)        { second = best; si = bi; best = v; bi = e; }
            else if (v > second) { second = v; si = e; }
        }
        float r  = __expf(second - best);   // softmax denom cancels in the ratio
        float w0 = 1.f / (1.f + r);
        float w1 = r / (1.f + r);
        const int tgl = tb0 + t;
        weights[2 * tgl + 0] = w0;
        weights[2 * tgl + 1] = w1;
        idxf[2 * tgl + 0] = (float)bi;
        idxf[2 * tgl + 1] = (float)si;
        selA[t] = bi;
        selB[t] = si;
    }
    __syncthreads();

    // mask: 64 experts x 2 k x 32 tokens; thread -> 4 (e,k) pairs x 4 tokens (float4)
    const int t8 = tid & 7;          // token group of 4 (8 groups = 32 tokens)
    const int pg = tid >> 3;         // 0..31, 4 pairs each
    const int b0 = 4 * t8;
    int sA0 = selA[b0+0], sA1 = selA[b0+1], sA2 = selA[b0+2], sA3 = selA[b0+3];
    int sB0 = selB[b0+0], sB1 = selB[b0+1], sB2 = selB[b0+2], sB3 = selB[b0+3];
#pragma unroll
    for (int p = 0; p < 4; ++p) {
        const int pair = pg * 4 + p;
        const int e = pair >> 1;
        const int k = pair & 1;
        const int a0 = k ? sB0 : sA0, a1 = k ? sB1 : sA1, a2 = k ? sB2 : sA2, a3 = k ? sB3 : sA3;
        float4 v;
        v.x = (a0 == e) ? 1.f : 0.f;
        v.y = (a1 == e) ? 1.f : 0.f;
        v.z = (a2 == e) ? 1.f : 0.f;
        v.w = (a3 == e) ? 1.f : 0.f;
        *(float4*)&mask[((size_t)e * 2 + k) * NTOK + tb0 + b0] = v;
    }
}

extern "C" void kernel_launch(void* const* d_in, const int* in_sizes, int n_in,
                              void* d_out, int out_size, void* d_ws, size_t ws_size,
                              hipStream_t stream) {
    const float* x  = (const float*)d_in[0];   // [16384, 2048]
    const float* gw = (const float*)d_in[1];   // [64, 2048]
    const float* gb = (const float*)d_in[2];   // [64]

    float* out     = (float*)d_out;
    float* logits  = out;                                  // 1048576
    float* weights = out + (size_t)NTOK * NEXP;            // 32768
    float* idxf    = weights + (size_t)NTOK * 2;           // 32768
    float* mask    = idxf + (size_t)NTOK * 2;              // 2097152

    // ws layout: wh | wl (256 KB each)
    uint4* wh = (uint4*)d_ws;
    uint4* wl = wh + 16384;

    prep_kernel<<<64, 256, 0, stream>>>(gw, wh, wl);
    fused_kernel<<<NTOK / 32, 256, 0, stream>>>(x, wh, wl, gb, logits, weights, idxf, mask);
}

// Round 6
// 51.698 us; speedup vs baseline: 1.0702x; 1.0702x over previous
//
#include <hip/hip_runtime.h>
#include <hip/hip_bf16.h>
#include <math.h>

#define HIDDEN 2048
#define NEXP   64
#define NTOK   16384
#define NTGF   512

typedef __attribute__((ext_vector_type(8))) _Float16 f16x8;  // 8 f16 = 4 VGPR (MFMA A/B frag)
typedef __attribute__((ext_vector_type(4))) float   f32x4;   // MFMA C/D frag

// 2-way fp16 RNE split: x = h + l + O(2^-22). Residual exact (Sterbenz), l may be subnormal (ok).
__device__ __forceinline__ void split2_f16(float4 f0, float4 f1, f16x8& h, f16x8& l) {
    float e[8] = {f0.x, f0.y, f0.z, f0.w, f1.x, f1.y, f1.z, f1.w};
    f16x8 hv, lv;
#pragma unroll
    for (int i = 0; i < 8; ++i) {
        _Float16 hh = (_Float16)e[i];        // v_cvt_f16_f32 (RNE)
        float r = e[i] - (float)hh;          // exact residual
        hv[i] = hh;
        lv[i] = (_Float16)r;
    }
    h = hv; l = lv;
}

// ---------------- Kernel 0: w [64][2048] fp32 -> wh/wl f16x8 slots, pre-swizzled ----------------
// Slot (c, e, kgp) holds w[e][c*64 + (kgp^(e&7))*8 .. +7]; flat = c*512 + e*8 + kgp.
// Linear LDS image for global_load_lds; XOR keeps B ds_read_b128 at 2-way (free).
__global__ __launch_bounds__(256) void prep_kernel(
    const float* __restrict__ gw, uint4* __restrict__ wh, uint4* __restrict__ wl)
{
    const int gid = blockIdx.x * 256 + threadIdx.x;   // 0..16383
    const int c   = gid >> 9;
    const int e   = (gid >> 3) & 63;
    const int kgp = gid & 7;
    const int kg  = kgp ^ (e & 7);
    const float* src = gw + (size_t)e * HIDDEN + c * 64 + kg * 8;
    float4 s0 = *(const float4*)src;
    float4 s1 = *(const float4*)(src + 4);
    f16x8 h, l;
    split2_f16(s0, s1, h, l);
    wh[gid] = __builtin_bit_cast(uint4, h);
    wl[gid] = __builtin_bit_cast(uint4, l);
}

// ---------------- Kernel A: split-K MFMA GEMM, BK=128 chunks, counted-vmcnt pipeline ----------
// R0 skeleton (minimal request volume: A 134 MB no-dup + B 67 MB + partials 32 MB) with the
// serialization removed: R0 drained vmcnt(0) at each of 8 chunk barriers (lockstep ~30 us gemm).
// Here: BK=128 (nch=4), dbuf-2, end-of-chunk s_waitcnt vmcnt(16) retires only the B-stage and
// keeps the 16 A-loads of chunk c+1 in flight across the raw barrier. 48 MFMA + 8 splits per
// chunk per wave (~1600 cy) cover the staged-load latency; 4 barriers per block total.
// grid (NTOK/128, KS) x 256 thr, 2 blocks/CU. Wave: 32 tokens (2 m-reps) x 64 experts.
#define STAGE128(cc, bo)                                                                         \
    _Pragma("unroll")                                                                            \
    for (int rr = 0; rr < 4; ++rr) {                                                             \
        const int s = rr * 256 + tid;                                                            \
        __builtin_amdgcn_global_load_lds(                                                        \
            (const __attribute__((address_space(1))) void*)(wh + (size_t)(cg0 + 2 * (cc)) * 512 + s), \
            (__attribute__((address_space(3))) void*)&Bs[(bo) + s], 16, 0, 0);                   \
        __builtin_amdgcn_global_load_lds(                                                        \
            (const __attribute__((address_space(1))) void*)(wl + (size_t)(cg0 + 2 * (cc)) * 512 + s), \
            (__attribute__((address_space(3))) void*)&Bs[(bo) + 1024 + s], 16, 0, 0);            \
    }

template<int NCH>   // chunks of 128 k; klen = NCH*128
__global__ __launch_bounds__(256, 2) void gemm_kernel(
    const float* __restrict__ x,     // [NTOK, HIDDEN]
    const uint4* __restrict__ wh,    // [32][64][8] slots (f16 high plane)
    const uint4* __restrict__ wl,    // f16 low plane
    float* __restrict__ part)        // [KS][NTOK][64]
{
    __shared__ uint4 Bs[2 * 2048];   // 2 bufs x ([h 1024][l 1024] slots) = 64 KB

    const int tid = threadIdx.x;
    const int l   = tid & 63;
    const int wv  = tid >> 6;
    const int kg  = blockIdx.y;
    const int kbase = kg * (NCH * 128);
    const int cg0   = kbase >> 6;    // 64-k group base
    const int t0    = blockIdx.x * 128 + wv * 32;

    // A: lane l -> rows t0+(l&15), t0+16+(l&15); k-group (l>>4)*8 within each 32-k step
    const float4* xp0 = (const float4*)(x + (size_t)(t0 + (l & 15)) * HIDDEN + kbase) + ((l >> 4) * 2);
    const float4* xp1 = (const float4*)(x + (size_t)(t0 + 16 + (l & 15)) * HIDDEN + kbase) + ((l >> 4) * 2);

    // B slot base: e=(l&15)+16eg, kgp=((k32<<2)|(l>>4))^(l&7); k32 XOR'd at use
    const int lb = ((l & 15) << 3) | ((l >> 4) ^ (l & 7));

    f32x4 acc1[2][4], acc2[2][4];    // [m-rep][eg]
#pragma unroll
    for (int r = 0; r < 2; ++r)
#pragma unroll
        for (int eg = 0; eg < 4; ++eg) {
            acc1[r][eg] = (f32x4){0.f, 0.f, 0.f, 0.f};
            acc2[r][eg] = (f32x4){0.f, 0.f, 0.f, 0.f};
        }

    float4 a[2][8], n[2][8];

    // prologue: stage chunk 0 -> buf 0 [8 ops]; load chunk 0's A [16 ops]
    STAGE128(0, 0)
#pragma unroll
    for (int j = 0; j < 4; ++j) {
        a[0][2 * j] = xp0[j * 8]; a[0][2 * j + 1] = xp0[j * 8 + 1];
        a[1][2 * j] = xp1[j * 8]; a[1][2 * j + 1] = xp1[j * 8 + 1];
    }
    asm volatile("s_waitcnt vmcnt(16)" ::: "memory");   // stage0 landed; A0 still in flight
    __builtin_amdgcn_s_barrier();
    __builtin_amdgcn_sched_barrier(0);

#pragma unroll
    for (int c = 0; c < NCH; ++c) {
        const int buf = c & 1;
        if (c + 1 < NCH) {
            STAGE128(c + 1, (buf ^ 1) * 2048)
            const int fb = (c + 1) * 32;
#pragma unroll
            for (int j = 0; j < 4; ++j) {
                n[0][2 * j] = xp0[fb + j * 8]; n[0][2 * j + 1] = xp0[fb + j * 8 + 1];
                n[1][2 * j] = xp1[fb + j * 8]; n[1][2 * j + 1] = xp1[fb + j * 8 + 1];
            }
        }

        // compute chunk c: 4 x 32-k steps, 48 MFMAs (compiler waits only for A(c))
#pragma unroll
        for (int ks = 0; ks < 4; ++ks) {
            f16x8 ah0, al0, ah1, al1;
            split2_f16(a[0][2 * ks], a[0][2 * ks + 1], ah0, al0);
            split2_f16(a[1][2 * ks], a[1][2 * ks + 1], ah1, al1);
            const int ib = buf * 2048 + (ks >> 1) * 512 + (lb ^ ((ks & 1) << 2));
#pragma unroll
            for (int eg = 0; eg < 4; ++eg) {
                f16x8 bh = __builtin_bit_cast(f16x8, Bs[ib + eg * 128]);
                f16x8 bl = __builtin_bit_cast(f16x8, Bs[ib + 1024 + eg * 128]);
                acc1[0][eg] = __builtin_amdgcn_mfma_f32_16x16x32_f16(ah0, bh, acc1[0][eg], 0, 0, 0); // hh
                acc2[0][eg] = __builtin_amdgcn_mfma_f32_16x16x32_f16(ah0, bl, acc2[0][eg], 0, 0, 0); // hl
                acc2[0][eg] = __builtin_amdgcn_mfma_f32_16x16x32_f16(al0, bh, acc2[0][eg], 0, 0, 0); // lh
                acc1[1][eg] = __builtin_amdgcn_mfma_f32_16x16x32_f16(ah1, bh, acc1[1][eg], 0, 0, 0);
                acc2[1][eg] = __builtin_amdgcn_mfma_f32_16x16x32_f16(ah1, bl, acc2[1][eg], 0, 0, 0);
                acc2[1][eg] = __builtin_amdgcn_mfma_f32_16x16x32_f16(al1, bh, acc2[1][eg], 0, 0, 0);
            }
        }

        if (c + 1 < NCH) {
            // retire STAGE(c+1) only; keep the 16 A(c+1) loads in flight across the barrier
            asm volatile("s_waitcnt vmcnt(16)" ::: "memory");
            __builtin_amdgcn_s_barrier();
            __builtin_amdgcn_sched_barrier(0);
#pragma unroll
            for (int m = 0; m < 2; ++m)
#pragma unroll
                for (int j = 0; j < 8; ++j) a[m][j] = n[m][j];
        }
    }

    // store: m-rep r, reg (eg,i) -> token t0 + r*16 + (l>>4)*4 + i, expert eg*16 + (l&15)
    float* pp = part + ((size_t)kg * NTOK + t0) * NEXP;
#pragma unroll
    for (int r = 0; r < 2; ++r)
#pragma unroll
        for (int eg = 0; eg < 4; ++eg)
#pragma unroll
            for (int i = 0; i < 4; ++i)
                pp[(size_t)(r * 16 + (l >> 4) * 4 + i) * NEXP + eg * 16 + (l & 15)] =
                    acc1[r][eg][i] + acc2[r][eg][i];
}

// ---------------- Kernel B: reduce partials + bias + top-2 + weights + mask ----------------
// 512 blocks x 32 tokens (2 blocks/CU, 8 waves/CU) for latency cover on partial reads.
__global__ __launch_bounds__(256) void finish_kernel(
    const float* __restrict__ part,   // [KS][NTOK][64]
    const float* __restrict__ bias_g,
    float* __restrict__ logits,
    float* __restrict__ weights,
    float* __restrict__ idxf,
    float* __restrict__ mask,
    int KS)
{
    __shared__ float Ls[32][65];
    __shared__ int selA[32], selB[32];

    const int tid = threadIdx.x;
    const int bm0 = blockIdx.x * 32;
    const int tn  = tid & 15;        // expert group of 4
    const int tm  = tid >> 4;        // 16 row-groups; each owns rows tm and tm+16

    float4 acc[2];
#pragma unroll
    for (int i = 0; i < 2; ++i) acc[i] = make_float4(0.f, 0.f, 0.f, 0.f);

    for (int kg = 0; kg < KS; ++kg) {
        const float* pb = part + ((size_t)kg * NTOK + bm0) * NEXP;
#pragma unroll
        for (int i = 0; i < 2; ++i) {
            float4 v = *(const float4*)&pb[(tm + 16 * i) * NEXP + 4 * tn];
            acc[i].x += v.x; acc[i].y += v.y; acc[i].z += v.z; acc[i].w += v.w;
        }
    }

    const float4 bv = *(const float4*)&bias_g[4 * tn];
#pragma unroll
    for (int i = 0; i < 2; ++i) {
        const int m = tm + 16 * i;
        float4 v;
        v.x = acc[i].x + bv.x;
        v.y = acc[i].y + bv.y;
        v.z = acc[i].z + bv.z;
        v.w = acc[i].w + bv.w;
        *(float4*)&logits[(size_t)(bm0 + m) * NEXP + 4 * tn] = v;
        Ls[m][4 * tn + 0] = v.x;
        Ls[m][4 * tn + 1] = v.y;
        Ls[m][4 * tn + 2] = v.z;
        Ls[m][4 * tn + 3] = v.w;
    }
    __syncthreads();

    if (tid < 32) {
        const int t = tid;
        float best = -1e30f, second = -1e30f;
        int bi = 0, si = 0;
#pragma unroll
        for (int e = 0; e < NEXP; ++e) {
            float v = Ls[t][e];
            if (v > best)        { second = best; si = bi; best = v; bi = e; }
            else if (v > second) { second = v; si = e; }
        }
        float r  = __expf(second - best);   // softmax denom cancels in the ratio
        float w0 = 1.f / (1.f + r);
        float w1 = r / (1.f + r);
        const int tgl = bm0 + t;
        weights[2 * tgl + 0] = w0;
        weights[2 * tgl + 1] = w1;
        idxf[2 * tgl + 0] = (float)bi;
        idxf[2 * tgl + 1] = (float)si;
        selA[t] = bi;
        selB[t] = si;
    }
    __syncthreads();

    // mask: 64 experts x 2 k x 32 tokens; thread -> 4 (e,k) pairs x 4 tokens (float4)
    const int t8 = tid & 7;          // token group of 4 (8 groups = 32 tokens)
    const int pg = tid >> 3;         // 0..31, 4 pairs each
    const int b0 = 4 * t8;
    int sA0 = selA[b0+0], sA1 = selA[b0+1], sA2 = selA[b0+2], sA3 = selA[b0+3];
    int sB0 = selB[b0+0], sB1 = selB[b0+1], sB2 = selB[b0+2], sB3 = selB[b0+3];
#pragma unroll
    for (int p = 0; p < 4; ++p) {
        const int pair = pg * 4 + p;
        const int e = pair >> 1;
        const int k = pair & 1;
        const int a0 = k ? sB0 : sA0, a1 = k ? sB1 : sA1, a2 = k ? sB2 : sA2, a3 = k ? sB3 : sA3;
        float4 v;
        v.x = (a0 == e) ? 1.f : 0.f;
        v.y = (a1 == e) ? 1.f : 0.f;
        v.z = (a2 == e) ? 1.f : 0.f;
        v.w = (a3 == e) ? 1.f : 0.f;
        *(float4*)&mask[((size_t)e * 2 + k) * NTOK + bm0 + b0] = v;
    }
}

extern "C" void kernel_launch(void* const* d_in, const int* in_sizes, int n_in,
                              void* d_out, int out_size, void* d_ws, size_t ws_size,
                              hipStream_t stream) {
    const float* x  = (const float*)d_in[0];   // [16384, 2048]
    const float* gw = (const float*)d_in[1];   // [64, 2048]
    const float* gb = (const float*)d_in[2];   // [64]

    float* out     = (float*)d_out;
    float* logits  = out;                                  // 1048576
    float* weights = out + (size_t)NTOK * NEXP;            // 32768
    float* idxf    = weights + (size_t)NTOK * 2;           // 32768
    float* mask    = idxf + (size_t)NTOK * 2;              // 2097152

    // ws layout: wh | wl (256 KB each) | partials (4 x 4 MB)
    uint4* wh = (uint4*)d_ws;
    uint4* wl = wh + 16384;
    const size_t hdrB   = 2 * 16384 * sizeof(uint4);               // 512 KB
    const size_t sliceB = (size_t)NTOK * NEXP * sizeof(float);     // 4 MB

    prep_kernel<<<64, 256, 0, stream>>>(gw, wh, wl);

    if (ws_size >= hdrB + 4 * sliceB) {
        float* part = (float*)((char*)d_ws + hdrB);
        gemm_kernel<4><<<dim3(NTOK / 128, 4), 256, 0, stream>>>(x, wh, wl, part);
        finish_kernel<<<NTGF, 256, 0, stream>>>(part, gb, logits, weights, idxf, mask, 4);
    } else {
        // fallback: single K-slice, partials = logits (finish adds bias in-place)
        gemm_kernel<16><<<dim3(NTOK / 128, 1), 256, 0, stream>>>(x, wh, wl, logits);
        finish_kernel<<<NTGF, 256, 0, stream>>>(logits, gb, logits, weights, idxf, mask, 1);
    }
}